// Round 4
// baseline (1772.538 us; speedup 1.0000x reference)
//
#include <hip/hip_runtime.h>

// EqProp MLP relaxation (784->128->128->10, B=16384, T=60), FUSED all-FP32 kernel.
// PRECISION FINDING (prev session): W1 ~ N(0,1/128) puts the tanh relaxation at
// the edge of chaos; (I-J)^-1 amplifies bias ~260x; per-step state quantization
// accumulates. Everything stays fp32-grade.
// R3 POST-MORTEM: weights-in-LDS removed the L2 wall (2683->1636us) but
// Occupancy=12% (1 wave/SIMD): every ds_read->FMA dep stalls the SIMD, VALU
// idles 47%. R4: single W1 copy serves BOTH GEMM patterns:
//   g1 reads W1[k][j0..j0+3]  (whole row, lanes span cols)   -> conflict-free
//   g2 reads W1[j][k..k+3]    (lanes = different rows, same col-range) -> T2 case
// Per-row chunk XOR-swizzle c4' = c4 ^ ((row>>2)&7): row-reads stay a lane
// permutation (conflict-free), column-slice reads spread over all 8 b128 slots
// (4-way, ~1.58x, optimal for 32 lanes). Deletes W1T (64 KB) AND k_prep_t.
// LDS = 64K W1 + 8K h1 + 8K h2 = exactly 81920 B -> 2 blocks/CU -> 2 waves/SIMD,
// and the two resident blocks are barrier-independent (phase overlap).
// NT=256, ROWS=16, 2-row x 4-col thread tiles, 1024 blocks.
//   h1' = tanh(c1 + h2@W1)          c1 = x@W0^T+b0 in REGISTERS (loop-invariant)
//   h2' = tanh(b1 + h1@W1^T + h3@W2)   h3 state in REGISTERS (lanes jg<10,
//   h3' = tanh(b2 + h2@W2^T)           broadcast via __shfl width=32)

#define NB 16384
#define D0 784
#define D1 128
#define D3 10
#define TSTEPS 60
#define NT 256
#define ROWS 16
#define NBLK (NB / ROWS)                 // 1024 blocks
#define H2O ((size_t)NB * D1)
#define H3O ((size_t)2 * NB * D1)
#define XS_LD 68   // padded x-staging stride, 16B-aligned rows

__device__ __forceinline__ float ftanh(float x)
{
    // tanh(x) = 1 - 2/(exp(2x)+1); safe at +/-inf (rcp(inf)=0 -> 1; e->0 -> -1)
    float e = __expf(2.0f * x);                  // v_mul + v_exp_f32
    float r = __builtin_amdgcn_rcpf(e + 1.0f);   // v_rcp_f32, ~1 ulp
    return fmaf(-2.0f, r, 1.0f);
}

union F4 { float4 v; float f[4]; };

__global__ __launch_bounds__(NT, 2)      // 2 blocks/CU (CUDA semantics, R1 finding)
void k_fused(const float* __restrict__ x,
             const float* __restrict__ n1, const float* __restrict__ n2,
             const float* __restrict__ n3,
             const float* __restrict__ W0, const float* __restrict__ b0,
             const float* __restrict__ W1, const float* __restrict__ b1,
             const float* __restrict__ W2, const float* __restrict__ b2,
             float* __restrict__ out)
{
    __shared__ float W1L[D1 * D1];       // 64 KB, chunk-swizzled (see header)
    __shared__ float h1L[ROWS * D1];     // 8 KB
    __shared__ float h2L[ROWS * D1];     // 8 KB   -> total exactly 81920 B
    float* xs = W1L;                     // x staging aliases W1L (phase 1 only)

    const int tid = threadIdx.x;
    const int jg = tid & 31, rg = tid >> 5;      // jg: col group, rg: 0..7
    const int j0 = jg * 4, r0 = rg * 2;
    const int jg3 = (jg < D3) ? jg : 0;          // clamped W2 row (a3 jg>=10 unused)
    const size_t row0 = (size_t)blockIdx.x * ROWS;

    // ---------------- phase 1: c1 = x @ W0^T + b0, kept in registers
    float c1r[2][4];
    #pragma unroll
    for (int l = 0; l < 4; ++l) { c1r[0][l] = 0.f; c1r[1][l] = 0.f; }

    for (int ch = 0; ch < 13; ++ch) {            // 784 = 12*64 + 16
        const int kb = ch * 64;
        const int klen = (ch < 12) ? 64 : 16;
        const int nv4 = klen >> 2;
        for (int q = tid; q < ROWS * nv4; q += NT) {
            int r = q / nv4, c4 = q - r * nv4;
            *(float4*)&xs[r * XS_LD + 4 * c4] =
                *(const float4*)(x + (row0 + r) * D0 + kb + 4 * c4);
        }
        __syncthreads();
        for (int k = 0; k < klen; k += 4) {
            F4 xa, xb;
            xa.v = *(const float4*)&xs[(r0)     * XS_LD + k];
            xb.v = *(const float4*)&xs[(r0 + 1) * XS_LD + k];
            #pragma unroll
            for (int l = 0; l < 4; ++l) {
                F4 w; w.v = *(const float4*)(W0 + (size_t)(j0 + l) * D0 + kb + k);
                #pragma unroll
                for (int kk = 0; kk < 4; ++kk) {
                    c1r[0][l] = fmaf(xa.f[kk], w.f[kk], c1r[0][l]);
                    c1r[1][l] = fmaf(xb.f[kk], w.f[kk], c1r[1][l]);
                }
            }
        }
        __syncthreads();                 // last xs read done before W1L stage
    }
    float b1r[4];
    #pragma unroll
    for (int l = 0; l < 4; ++l) {
        float bb = b0[j0 + l];
        c1r[0][l] += bb; c1r[1][l] += bb;
        b1r[l] = b1[j0 + l];
    }
    const float b2r = (jg < D3) ? b2[jg] : 0.f;

    // ---------------- stage W1 into LDS, chunk-swizzled + init state
    // store W1[r][c] at chunk (r*32) | ((c>>2) ^ ((r>>2)&7))
    for (int q = tid; q < 4096; q += NT) {       // 16 float4 per thread
        int r = q >> 5, c4 = q & 31;
        int d = (r << 5) | (c4 ^ ((r >> 2) & 7));
        ((float4*)W1L)[d] = ((const float4*)W1)[q];   // LDS write: row-perm, no conflict
    }
    for (int q = tid; q < ROWS * 32; q += NT) {
        int r = q >> 5, c4 = q & 31;
        *(float4*)&h1L[r * D1 + 4 * c4] = *(const float4*)(n1 + (row0 + r) * D1 + 4 * c4);
        *(float4*)&h2L[r * D1 + 4 * c4] = *(const float4*)(n2 + (row0 + r) * D1 + 4 * c4);
    }
    float h3r[2];                                // h3 state in regs (lanes jg<10)
    #pragma unroll
    for (int i = 0; i < 2; ++i)
        h3r[i] = (jg < D3) ? n3[(row0 + r0 + i) * D3 + jg] : 0.f;
    __syncthreads();

    // ---------------- T synchronous Jacobi steps (2 barriers/step)
    const int xw2 = jg & 7;                      // per-lane row-swizzle for g2 reads
    for (int t = 0; t < TSTEPS; ++t) {
        float a1[2][4], a2[2][4], a3[2];
        #pragma unroll
        for (int l = 0; l < 4; ++l) {
            a1[0][l] = c1r[0][l]; a1[1][l] = c1r[1][l];
            a2[0][l] = b1r[l];    a2[1][l] = b1r[l];
        }
        a3[0] = b2r; a3[1] = b2r;

        for (int k = 0; k < D1; k += 4) {
            F4 p2[2], p1[2];
            p2[0].v = *(const float4*)&h2L[(r0)     * D1 + k];  // 2-addr broadcast: free
            p2[1].v = *(const float4*)&h2L[(r0 + 1) * D1 + k];
            p1[0].v = *(const float4*)&h1L[(r0)     * D1 + k];
            p1[1].v = *(const float4*)&h1L[(r0 + 1) * D1 + k];
            F4 w2r; w2r.v = *(const float4*)(W2 + (size_t)jg3 * D1 + k);  // L1-hot 5KB
            const int co1 = ((jg ^ ((k >> 2) & 7)) << 2);       // g1: row read, perm'd
            const int co2 = (((k >> 2) ^ xw2) << 2);            // g2: col-slice, 4-way
            F4 wb[4];
            #pragma unroll
            for (int l = 0; l < 4; ++l)                         // W1[j0+l][k..k+3]
                wb[l].v = *(const float4*)&W1L[(j0 + l) * D1 + co2];
            #pragma unroll
            for (int kk = 0; kk < 4; ++kk) {
                F4 wa;                                          // W1[k+kk][j0..j0+3]
                wa.v = *(const float4*)&W1L[(k + kk) * D1 + co1];
                #pragma unroll
                for (int i = 0; i < 2; ++i) {
                    #pragma unroll
                    for (int l = 0; l < 4; ++l) {
                        a1[i][l] = fmaf(p2[i].f[kk], wa.f[l],    a1[i][l]);
                        a2[i][l] = fmaf(p1[i].f[kk], wb[l].f[kk], a2[i][l]);
                    }
                    a3[i] = fmaf(p2[i].f[kk], w2r.f[kk], a3[i]); // g3 = b2 + h2@W2^T
                }
            }
        }
        #pragma unroll
        for (int kk = 0; kk < D3; ++kk) {        // g2 += h3 @ W2 (h3 via shfl bcast)
            F4 wc; wc.v = *(const float4*)(W2 + (size_t)kk * D1 + j0);
            #pragma unroll
            for (int i = 0; i < 2; ++i) {
                float h3v = __shfl(h3r[i], kk, 32);   // lane kk of same 32-lane group
                #pragma unroll
                for (int l = 0; l < 4; ++l)
                    a2[i][l] = fmaf(h3v, wc.f[l], a2[i][l]);
            }
        }
        __syncthreads();                         // all reads of old state complete
        #pragma unroll
        for (int i = 0; i < 2; ++i) {
            *(float4*)&h1L[(r0 + i) * D1 + j0] =
                make_float4(ftanh(a1[i][0]), ftanh(a1[i][1]), ftanh(a1[i][2]), ftanh(a1[i][3]));
            *(float4*)&h2L[(r0 + i) * D1 + j0] =
                make_float4(ftanh(a2[i][0]), ftanh(a2[i][1]), ftanh(a2[i][2]), ftanh(a2[i][3]));
            h3r[i] = ftanh(a3[i]);               // garbage for jg>=10, never read
        }
        __syncthreads();                         // new state visible
    }

    // ---------------- epilogue: (h1, h2, h3) fp32, coalesced
    for (int q = tid; q < ROWS * 32; q += NT) {
        int r = q >> 5, c4 = q & 31;
        *(float4*)(out + (row0 + r) * D1 + 4 * c4)       = *(const float4*)&h1L[r * D1 + 4 * c4];
        *(float4*)(out + H2O + (row0 + r) * D1 + 4 * c4) = *(const float4*)&h2L[r * D1 + 4 * c4];
    }
    if (jg < D3) {
        #pragma unroll
        for (int i = 0; i < 2; ++i)
            out[H3O + (row0 + r0 + i) * D3 + jg] = h3r[i];
    }
}

extern "C" void kernel_launch(void* const* d_in, const int* in_sizes, int n_in,
                              void* d_out, int out_size, void* d_ws, size_t ws_size,
                              hipStream_t stream) {
    // inputs: 0:x 1:y 2:n1 3:n2 4:n3 5:W0 6:b0 7:W1 8:b1 9:W2 10:b2 11:T(=60 hard-coded)
    const float* x  = (const float*)d_in[0];
    const float* n1 = (const float*)d_in[2];
    const float* n2 = (const float*)d_in[3];
    const float* n3 = (const float*)d_in[4];
    const float* W0 = (const float*)d_in[5];
    const float* b0 = (const float*)d_in[6];
    const float* W1 = (const float*)d_in[7];
    const float* b1 = (const float*)d_in[8];
    const float* W2 = (const float*)d_in[9];
    const float* b2 = (const float*)d_in[10];

    k_fused<<<NBLK, NT, 0, stream>>>(x, n1, n2, n3, W0, b0, W1, b1, W2, b2,
                                     (float*)d_out);

    hipError_t e = hipGetLastError();
    if (e != hipSuccess) {   // surface launch error as fp32 1000+e (free on success)
        static float code[4];
        code[0] = code[1] = code[2] = code[3] = 1000.0f + (float)(int)e;
        hipMemcpyAsync(d_out, code, 4 * sizeof(float), hipMemcpyHostToDevice, stream);
    }
}

// Round 5
// 1384.967 us; speedup vs baseline: 1.2798x; 1.2798x over previous
//
#include <hip/hip_runtime.h>

// EqProp MLP relaxation (784->128->128->10, B=16384, T=60), FUSED all-FP32 kernel.
// PRECISION FINDING (prev session): W1 ~ N(0,1/128) puts the tanh relaxation at
// the edge of chaos; (I-J)^-1 amplifies bias ~260x; per-step state quantization
// accumulates. Everything stays fp32-grade.
// R4 POST-MORTEM: 8-value swizzle (c4 ^ (r>>2)&7) left lanes {jg,jg+8,jg+16,
// jg+24} on the same 4-bank group -> 4-way conflict (1.26e8 extra cy), and
// R=2 tiles halved rows-per-b128 amortization. R3 had tile economy, R4 had
// occupancy; R5 takes both + a correct swizzle:
//   * FULL 5-bit swizzle: chunk of W1[r][c] stored at c4 ^ (r>>2), r>>2 in
//     0..31. g2 col-slice read (lane jg -> row 4jg+l) lands on chunk
//     (k>>2)^jg: distinct for ALL 32 lanes -> 0 conflicts. g1 row read is an
//     intra-row permutation of a contiguous 512B region -> 0 conflicts.
//     Both reads use the SAME offset co = (jg ^ (k>>2)) << 2.
//   * ROWS=64, NT=512 (8 waves), 4-row x 4-col thread tiles. LDS = 64K W1 +
//     32K h1 + 32K h2 = 128KB -> 1 block/CU, 2 waves/SIMD; grid = 256 blocks
//     = exactly 1/CU (no tail). Per wave per k-iter: 16 b128 : 144 FMA.
//   h1' = tanh(c1 + h2@W1)          c1 = x@W0^T+b0 in REGISTERS (loop-invariant)
//   h2' = tanh(b1 + h1@W1^T + h3@W2)   h3 state in REGISTERS (lanes jg<10,
//   h3' = tanh(b2 + h2@W2^T)           broadcast via __shfl width=32)

#define NB 16384
#define D0 784
#define D1 128
#define D3 10
#define TSTEPS 60
#define NT 512
#define ROWS 64
#define NBLK (NB / ROWS)                 // 256 blocks = 1 per CU
#define H2O ((size_t)NB * D1)
#define H3O ((size_t)2 * NB * D1)
#define XS_LD 68   // padded x-staging stride, 16B-aligned rows

__device__ __forceinline__ float ftanh(float x)
{
    // tanh(x) = 1 - 2/(exp(2x)+1); safe at +/-inf (rcp(inf)=0 -> 1; e->0 -> -1)
    float e = __expf(2.0f * x);                  // v_mul + v_exp_f32
    float r = __builtin_amdgcn_rcpf(e + 1.0f);   // v_rcp_f32, ~1 ulp
    return fmaf(-2.0f, r, 1.0f);
}

union F4 { float4 v; float f[4]; };

__global__ __launch_bounds__(NT, 1)      // 1 block/CU; VGPR cap 256 (2 waves/SIMD)
void k_fused(const float* __restrict__ x,
             const float* __restrict__ n1, const float* __restrict__ n2,
             const float* __restrict__ n3,
             const float* __restrict__ W0, const float* __restrict__ b0,
             const float* __restrict__ W1, const float* __restrict__ b1,
             const float* __restrict__ W2, const float* __restrict__ b2,
             float* __restrict__ out)
{
    __shared__ float W1L[D1 * D1];       // 64 KB, full-period chunk swizzle
    __shared__ float h1L[ROWS * D1];     // 32 KB
    __shared__ float h2L[ROWS * D1];     // 32 KB   -> total 131072 B
    float* xs = W1L;                     // x staging aliases W1L (phase 1 only;
                                         // needs 64*68*4B = 17.4KB < 64KB)

    const int tid = threadIdx.x;
    const int jg = tid & 31, rg = tid >> 5;      // jg: col group, rg: 0..15
    const int j0 = jg * 4, r0 = rg * 4;
    const int jg3 = (jg < D3) ? jg : 0;          // clamped W2 row (a3 jg>=10 unused)
    const size_t row0 = (size_t)blockIdx.x * ROWS;

    // ---------------- phase 1: c1 = x @ W0^T + b0, kept in registers
    float c1r[4][4];
    #pragma unroll
    for (int i = 0; i < 4; ++i)
        #pragma unroll
        for (int l = 0; l < 4; ++l) c1r[i][l] = 0.f;

    for (int ch = 0; ch < 13; ++ch) {            // 784 = 12*64 + 16
        const int kb = ch * 64;
        const int klen = (ch < 12) ? 64 : 16;
        const int nv4 = klen >> 2;
        for (int q = tid; q < ROWS * nv4; q += NT) {
            int r = q / nv4, c4 = q - r * nv4;
            *(float4*)&xs[r * XS_LD + 4 * c4] =
                *(const float4*)(x + (row0 + r) * D0 + kb + 4 * c4);
        }
        __syncthreads();
        for (int k = 0; k < klen; k += 4) {
            F4 xr[4];
            #pragma unroll
            for (int i = 0; i < 4; ++i)
                xr[i].v = *(const float4*)&xs[(r0 + i) * XS_LD + k];
            #pragma unroll
            for (int l = 0; l < 4; ++l) {
                F4 w; w.v = *(const float4*)(W0 + (size_t)(j0 + l) * D0 + kb + k);
                #pragma unroll
                for (int kk = 0; kk < 4; ++kk)
                    #pragma unroll
                    for (int i = 0; i < 4; ++i)
                        c1r[i][l] = fmaf(xr[i].f[kk], w.f[kk], c1r[i][l]);
            }
        }
        __syncthreads();                 // last xs read done before W1L stage
    }
    float b1r[4];
    #pragma unroll
    for (int l = 0; l < 4; ++l) {
        float bb = b0[j0 + l];
        #pragma unroll
        for (int i = 0; i < 4; ++i) c1r[i][l] += bb;
        b1r[l] = b1[j0 + l];
    }
    const float b2r = (jg < D3) ? b2[jg] : 0.f;

    // ---------------- stage W1 into LDS (full-period swizzle) + init state
    // chunk of W1[r][c] stored at (r<<5) | ((c>>2) ^ (r>>2)); r>>2 spans 0..31.
    for (int q = tid; q < 4096; q += NT) {       // 8 float4 per thread
        int r = q >> 5, c4 = q & 31;
        int d = (r << 5) | (c4 ^ (r >> 2));
        ((float4*)W1L)[d] = ((const float4*)W1)[q];  // row-perm write: no conflict
    }
    for (int q = tid; q < ROWS * 32; q += NT) {
        int r = q >> 5, c4 = q & 31;
        *(float4*)&h1L[r * D1 + 4 * c4] = *(const float4*)(n1 + (row0 + r) * D1 + 4 * c4);
        *(float4*)&h2L[r * D1 + 4 * c4] = *(const float4*)(n2 + (row0 + r) * D1 + 4 * c4);
    }
    float h3r[4];                                // h3 state in regs (lanes jg<10)
    #pragma unroll
    for (int i = 0; i < 4; ++i)
        h3r[i] = (jg < D3) ? n3[(row0 + r0 + i) * D3 + jg] : 0.f;
    __syncthreads();

    // ---------------- T synchronous Jacobi steps (2 barriers/step)
    for (int t = 0; t < TSTEPS; ++t) {
        float a1[4][4], a2[4][4], a3[4];
        #pragma unroll
        for (int i = 0; i < 4; ++i) {
            #pragma unroll
            for (int l = 0; l < 4; ++l) { a1[i][l] = c1r[i][l]; a2[i][l] = b1r[l]; }
            a3[i] = b2r;
        }

        for (int k = 0; k < D1; k += 4) {
            F4 p2[4], p1[4];
            #pragma unroll
            for (int i = 0; i < 4; ++i) {
                p2[i].v = *(const float4*)&h2L[(r0 + i) * D1 + k];  // 2-addr bcast
                p1[i].v = *(const float4*)&h1L[(r0 + i) * D1 + k];
            }
            F4 w2r; w2r.v = *(const float4*)(W2 + (size_t)jg3 * D1 + k);  // L1-hot 5KB
            const int co = ((jg ^ (k >> 2)) << 2);  // SAME offset serves g1 and g2
            F4 wb[4];
            #pragma unroll
            for (int l = 0; l < 4; ++l)             // g2: W1[j0+l][k..k+3], 32 distinct
                wb[l].v = *(const float4*)&W1L[(j0 + l) * D1 + co];   // chunks: 0-conflict
            #pragma unroll
            for (int kk = 0; kk < 4; ++kk) {
                F4 wa;                              // g1: W1[k+kk][j0..j0+3], row perm
                wa.v = *(const float4*)&W1L[(k + kk) * D1 + co];
                #pragma unroll
                for (int i = 0; i < 4; ++i) {
                    #pragma unroll
                    for (int l = 0; l < 4; ++l) {
                        a1[i][l] = fmaf(p2[i].f[kk], wa.f[l],     a1[i][l]);
                        a2[i][l] = fmaf(p1[i].f[kk], wb[l].f[kk], a2[i][l]);
                    }
                    a3[i] = fmaf(p2[i].f[kk], w2r.f[kk], a3[i]);  // g3 = b2 + h2@W2^T
                }
            }
        }
        #pragma unroll
        for (int kk = 0; kk < D3; ++kk) {        // g2 += h3 @ W2 (h3 via shfl bcast)
            F4 wc; wc.v = *(const float4*)(W2 + (size_t)kk * D1 + j0);
            #pragma unroll
            for (int i = 0; i < 4; ++i) {
                float h3v = __shfl(h3r[i], kk, 32);   // lane kk of same 32-lane group
                #pragma unroll
                for (int l = 0; l < 4; ++l)
                    a2[i][l] = fmaf(h3v, wc.f[l], a2[i][l]);
            }
        }
        __syncthreads();                         // all reads of old state complete
        #pragma unroll
        for (int i = 0; i < 4; ++i) {
            *(float4*)&h1L[(r0 + i) * D1 + j0] =
                make_float4(ftanh(a1[i][0]), ftanh(a1[i][1]), ftanh(a1[i][2]), ftanh(a1[i][3]));
            *(float4*)&h2L[(r0 + i) * D1 + j0] =
                make_float4(ftanh(a2[i][0]), ftanh(a2[i][1]), ftanh(a2[i][2]), ftanh(a2[i][3]));
            h3r[i] = ftanh(a3[i]);               // garbage for jg>=10, never read
        }
        __syncthreads();                         // new state visible
    }

    // ---------------- epilogue: (h1, h2, h3) fp32, coalesced
    for (int q = tid; q < ROWS * 32; q += NT) {
        int r = q >> 5, c4 = q & 31;
        *(float4*)(out + (row0 + r) * D1 + 4 * c4)       = *(const float4*)&h1L[r * D1 + 4 * c4];
        *(float4*)(out + H2O + (row0 + r) * D1 + 4 * c4) = *(const float4*)&h2L[r * D1 + 4 * c4];
    }
    if (jg < D3) {
        #pragma unroll
        for (int i = 0; i < 4; ++i)
            out[H3O + (row0 + r0 + i) * D3 + jg] = h3r[i];
    }
}

extern "C" void kernel_launch(void* const* d_in, const int* in_sizes, int n_in,
                              void* d_out, int out_size, void* d_ws, size_t ws_size,
                              hipStream_t stream) {
    // inputs: 0:x 1:y 2:n1 3:n2 4:n3 5:W0 6:b0 7:W1 8:b1 9:W2 10:b2 11:T(=60 hard-coded)
    const float* x  = (const float*)d_in[0];
    const float* n1 = (const float*)d_in[2];
    const float* n2 = (const float*)d_in[3];
    const float* n3 = (const float*)d_in[4];
    const float* W0 = (const float*)d_in[5];
    const float* b0 = (const float*)d_in[6];
    const float* W1 = (const float*)d_in[7];
    const float* b1 = (const float*)d_in[8];
    const float* W2 = (const float*)d_in[9];
    const float* b2 = (const float*)d_in[10];

    k_fused<<<NBLK, NT, 0, stream>>>(x, n1, n2, n3, W0, b0, W1, b1, W2, b2,
                                     (float*)d_out);

    hipError_t e = hipGetLastError();
    if (e != hipSuccess) {   // surface launch error as fp32 1000+e (free on success)
        static float code[4];
        code[0] = code[1] = code[2] = code[3] = 1000.0f + (float)(int)e;
        hipMemcpyAsync(d_out, code, 4 * sizeof(float), hipMemcpyHostToDevice, stream);
    }
}